// Round 4
// baseline (247.806 us; speedup 1.0000x reference)
//
#include <hip/hip_runtime.h>

// MultiHeadAttention B=2,S=2048,E=512,H=8,dh=64 — bf16 MFMA, split-K flash.
// Head mapping (VERIFIED r3): head h of batch b = contiguous [2048][64] span at
// flat offset (b*8+h)*S*64 of the projected [4096][512] tensor.
// R4 changes: (1) attention split-K x4 (grid 1024 -> 4 blocks/CU; was 1) with
// fp32 partial O + (m,l) and a combine pass — gated on ws_size, falling back
// to the r3 single-pass path; (2) proj 128x128 tiles (traffic 288->120 MB).
// Scale quirk: 1/sqrt(s_k) = 1/sqrt(2048).

#define SEQ 2048
#define EMB 512
#define DH  64
#define MROWS 4096
#define NROWS 32768   // 16 heads * 2048 rows of 64

typedef float  v4f __attribute__((ext_vector_type(4)));
typedef short  v8s __attribute__((ext_vector_type(8)));

static __device__ __forceinline__ unsigned int f2bf(float f) {
    unsigned int u = __float_as_uint(f);
    u += 0x7fffu + ((u >> 16) & 1u);       // RNE
    return u >> 16;
}
static __device__ __forceinline__ unsigned int pack2(float a, float b) {
    return f2bf(a) | (f2bf(b) << 16);
}

// ---------------------------------------------------------------------------
// Projection: C[m][n] = sum_k A[m][k]*W[n][k] + bias[n], bf16 out.
// 128(m) x 128(n) tile, BK=64. 4 waves x (32 m-rows, 2 groups of 16) x 8 cb.
// ---------------------------------------------------------------------------
__global__ __launch_bounds__(256, 2) void proj_kernel(
    const float* __restrict__ q, const float* __restrict__ k, const float* __restrict__ v,
    const float* __restrict__ Wq, const float* __restrict__ bq,
    const float* __restrict__ Wk, const float* __restrict__ bk,
    const float* __restrict__ Wv, const float* __restrict__ bv,
    unsigned short* __restrict__ Qbf, unsigned short* __restrict__ Kbf,
    unsigned short* __restrict__ Vbf)
{
    __shared__ __align__(16) char smem[36864];   // As 128x144 | Ws 128x144
    char* As = smem;
    char* Ws = smem + 18432;

    const int z = blockIdx.z;
    const float* A    = (z == 0) ? q  : (z == 1) ? k  : v;
    const float* W    = (z == 0) ? Wq : (z == 1) ? Wk : Wv;
    const float* bias = (z == 0) ? bq : (z == 1) ? bk : bv;
    unsigned short* Cg = (z == 0) ? Qbf : (z == 1) ? Kbf : Vbf;

    const int tid  = threadIdx.x;
    const int w    = tid >> 6;
    const int lane = tid & 63;
    const int qd   = lane >> 4;
    const int n    = lane & 15;
    const int nb = blockIdx.x;      // 0..3
    const int mb = blockIdx.y;      // 0..31
    const int m0 = mb * 128, n0 = nb * 128;

    const int rA = tid & 127, hA = tid >> 7;   // row, half(32 floats)

    float4 areg[8], wreg[8];
#pragma unroll
    for (int i = 0; i < 8; ++i) {
        areg[i] = *(const float4*)&A[(size_t)(m0 + rA) * EMB + hA * 32 + i * 4];
        wreg[i] = *(const float4*)&W[(size_t)(n0 + rA) * EMB + hA * 32 + i * 4];
    }

    v4f acc[2][8];
#pragma unroll
    for (int g = 0; g < 2; ++g)
#pragma unroll
        for (int cb = 0; cb < 8; ++cb) acc[g][cb] = (v4f)0.f;

#pragma unroll 1
    for (int kt = 0; kt < 8; ++kt) {
        __syncthreads();
#pragma unroll
        for (int i2 = 0; i2 < 4; ++i2) {
            uint4 pa = { pack2(areg[2*i2].x, areg[2*i2].y), pack2(areg[2*i2].z, areg[2*i2].w),
                         pack2(areg[2*i2+1].x, areg[2*i2+1].y), pack2(areg[2*i2+1].z, areg[2*i2+1].w) };
            *(uint4*)&As[rA * 144 + hA * 64 + i2 * 16] = pa;
            uint4 pw = { pack2(wreg[2*i2].x, wreg[2*i2].y), pack2(wreg[2*i2].z, wreg[2*i2].w),
                         pack2(wreg[2*i2+1].x, wreg[2*i2+1].y), pack2(wreg[2*i2+1].z, wreg[2*i2+1].w) };
            *(uint4*)&Ws[rA * 144 + hA * 64 + i2 * 16] = pw;
        }
        __syncthreads();

        if (kt + 1 < 8) {
#pragma unroll
            for (int i = 0; i < 8; ++i) {
                areg[i] = *(const float4*)&A[(size_t)(m0 + rA) * EMB + (kt+1) * 64 + hA * 32 + i * 4];
                wreg[i] = *(const float4*)&W[(size_t)(n0 + rA) * EMB + (kt+1) * 64 + hA * 32 + i * 4];
            }
        }

#pragma unroll
        for (int ks = 0; ks < 2; ++ks) {
            v8s af[2];
#pragma unroll
            for (int g = 0; g < 2; ++g)
                af[g] = *(const v8s*)&As[(w * 32 + g * 16 + n) * 144 + ks * 64 + qd * 16];
#pragma unroll
            for (int cb = 0; cb < 8; ++cb) {
                v8s bfr = *(const v8s*)&Ws[(cb * 16 + n) * 144 + ks * 64 + qd * 16];
#pragma unroll
                for (int g = 0; g < 2; ++g)
                    acc[g][cb] = __builtin_amdgcn_mfma_f32_16x16x32_bf16(af[g], bfr, acc[g][cb], 0, 0, 0);
            }
        }
    }

    float bb[8];
#pragma unroll
    for (int cb = 0; cb < 8; ++cb) bb[cb] = bias[n0 + cb * 16 + n];
#pragma unroll
    for (int g = 0; g < 2; ++g)
#pragma unroll
        for (int cb = 0; cb < 8; ++cb)
#pragma unroll
            for (int r = 0; r < 4; ++r) acc[g][cb][r] += bb[cb];

    __syncthreads();
    // bounce: Ct[128 rows][136 shorts pitch (272B)], then coalesced uint4 stores
    short* Ct = (short*)smem;
#pragma unroll
    for (int g = 0; g < 2; ++g)
#pragma unroll
        for (int cb = 0; cb < 8; ++cb)
#pragma unroll
            for (int r = 0; r < 4; ++r)
                Ct[(w * 32 + g * 16 + qd * 4 + r) * 136 + cb * 16 + n] =
                    (short)f2bf(acc[g][cb][r]);
    __syncthreads();
    const int rr = tid >> 1, hh = tid & 1;
#pragma unroll
    for (int i = 0; i < 8; ++i) {
        uint4 t4 = *(const uint4*)&smem[rr * 272 + hh * 128 + i * 16];
        *(uint4*)&Cg[(size_t)(m0 + rr) * EMB + n0 + hh * 64 + i * 8] = t4;
    }
}

// ---------------------------------------------------------------------------
// V transpose per head: contiguous [2048][64] head block -> VtG[bh][64][2048].
// ---------------------------------------------------------------------------
__global__ __launch_bounds__(256) void vtrans_kernel(
    const unsigned short* __restrict__ Vbf, unsigned short* __restrict__ VtG)
{
    __shared__ unsigned short T[64 * 136];
    const int bh = blockIdx.x, st = blockIdx.y;
    const int tid = threadIdx.x;
    const unsigned short* Vh = Vbf + (size_t)bh * (SEQ * DH) + (size_t)st * 128 * DH;
#pragma unroll
    for (int it = 0; it < 4; ++it) {
        int c = tid + it * 256;
        int s_l = c >> 3, ch = c & 7;
        uint4 t4 = *(const uint4*)&Vh[(size_t)s_l * DH + ch * 8];
        const unsigned short* e = (const unsigned short*)&t4;
#pragma unroll
        for (int j = 0; j < 8; ++j)
            T[(ch * 8 + j) * 136 + s_l] = e[j];
    }
    __syncthreads();
    const int d = tid >> 2, sq = tid & 3;
    unsigned short* Od = VtG + (size_t)bh * (DH * SEQ) + (size_t)d * SEQ + st * 128;
#pragma unroll
    for (int i = 0; i < 4; ++i) {
        uint4 t4 = *(const uint4*)&T[d * 136 + sq * 32 + i * 8];
        *(uint4*)&Od[sq * 32 + i * 8] = t4;
    }
}

// ---------------------------------------------------------------------------
// Flash attention, bf16 MFMA, transposed scores, optional split-K.
// SPLITS>1: blockIdx.z = kq handles 32/SPLITS K-tiles, writes unnormalized O
// (fp32, transposed to row-major) + per-row (m,l); combine_kernel merges.
// SPLITS==1: r3 behavior (normalize in epilogue, write d_out directly).
// ---------------------------------------------------------------------------
template <int SPLITS>
__global__ __launch_bounds__(256, 4) void attn_kernel(
    const unsigned short* __restrict__ Qbf, const unsigned short* __restrict__ Kbf,
    const unsigned short* __restrict__ VtG, const float* __restrict__ mask,
    float* __restrict__ Opart, float* __restrict__ ml, float* __restrict__ out)
{
    __shared__ __align__(16) char smem[36864];  // Ks 64x144 | Vts 64x144 | Ps 4x(32x144)
    char* Ks  = smem;
    char* Vts = smem + 9216;

    const int tid  = threadIdx.x;
    const int w    = tid >> 6;
    const int lane = tid & 63;
    const int qd   = lane >> 4;
    const int n    = lane & 15;
    char* Ps = smem + 18432 + w * 4608;

    const int bh = blockIdx.x;           // 0..15
    const int rb = blockIdx.y;           // 0..15
    const int kq = blockIdx.z;           // 0..SPLITS-1
    const int KT0 = kq * (32 / SPLITS), KT1 = KT0 + 32 / SPLITS;

    const unsigned short* Qh = Qbf + (size_t)bh * (SEQ * DH);
    const unsigned short* Kh = Kbf + (size_t)bh * (SEQ * DH);
    const unsigned short* Vth = VtG + (size_t)bh * (DH * SEQ);

    const float scale = 0.02209708691207961f;   // 1/sqrt(2048)

    v8s qf[2][2];
#pragma unroll
    for (int g = 0; g < 2; ++g) {
        const size_t qrow = (size_t)(rb * 128 + w * 32 + g * 16 + n);
#pragma unroll
        for (int ks = 0; ks < 2; ++ks)
            qf[g][ks] = *(const v8s*)&Qh[qrow * DH + ks * 32 + qd * 8];
    }

    const int sr = lane;
    uint4 kreg[2], vreg[2];
#pragma unroll
    for (int p = 0; p < 2; ++p) {
        kreg[p] = *(const uint4*)&Kh[(size_t)(KT0 * 64 + sr) * DH + (w * 2 + p) * 8];
        vreg[p] = *(const uint4*)&Vth[(size_t)sr * SEQ + KT0 * 64 + (w * 2 + p) * 8];
    }

    float m_[2] = { -1e30f, -1e30f }, l_[2] = { 0.f, 0.f };
    v4f oacc[2][4];
#pragma unroll
    for (int g = 0; g < 2; ++g)
#pragma unroll
        for (int cb = 0; cb < 4; ++cb) oacc[g][cb] = (v4f)0.f;

#pragma unroll 1
    for (int kt = KT0; kt < KT1; ++kt) {
        __syncthreads();
#pragma unroll
        for (int p = 0; p < 2; ++p) {
            *(uint4*)&Ks [sr * 144 + (w * 2 + p) * 16] = kreg[p];
            *(uint4*)&Vts[sr * 144 + (w * 2 + p) * 16] = vreg[p];
        }
        __syncthreads();

        if (kt + 1 < KT1) {
#pragma unroll
            for (int p = 0; p < 2; ++p) {
                kreg[p] = *(const uint4*)&Kh[(size_t)((kt + 1) * 64 + sr) * DH + (w * 2 + p) * 8];
                vreg[p] = *(const uint4*)&Vth[(size_t)sr * SEQ + (kt + 1) * 64 + (w * 2 + p) * 8];
            }
        }

        float4 mk[2][4];
#pragma unroll
        for (int g = 0; g < 2; ++g) {
            const size_t mrow = (size_t)(rb * 128 + w * 32 + g * 16 + n);
#pragma unroll
            for (int cb = 0; cb < 4; ++cb)
                mk[g][cb] = *(const float4*)&mask[mrow * SEQ + kt * 64 + cb * 16 + qd * 4];
        }

        v4f sacc[2][4];
#pragma unroll
        for (int g = 0; g < 2; ++g)
#pragma unroll
            for (int cb = 0; cb < 4; ++cb) sacc[g][cb] = (v4f)0.f;
#pragma unroll
        for (int ks = 0; ks < 2; ++ks)
#pragma unroll
            for (int cb = 0; cb < 4; ++cb) {
                v8s kf = *(const v8s*)&Ks[(cb * 16 + n) * 144 + ks * 64 + qd * 16];
#pragma unroll
                for (int g = 0; g < 2; ++g)
                    sacc[g][cb] = __builtin_amdgcn_mfma_f32_16x16x32_bf16(kf, qf[g][ks], sacc[g][cb], 0, 0, 0);
            }

#pragma unroll
        for (int g = 0; g < 2; ++g) {
            float sv[4][4];
            float mx = -1e30f;
#pragma unroll
            for (int cb = 0; cb < 4; ++cb)
#pragma unroll
                for (int r = 0; r < 4; ++r) {
                    float s = fmaf(sacc[g][cb][r], scale, ((const float*)&mk[g][cb])[r]);
                    sv[cb][r] = s;
                    mx = fmaxf(mx, s);
                }
            mx = fmaxf(mx, __shfl_xor(mx, 16));
            mx = fmaxf(mx, __shfl_xor(mx, 32));
            const float mnew  = fmaxf(m_[g], mx);
            const float alpha = __expf(m_[g] - mnew);
            float rs = 0.f;
            float pv[4][4];
#pragma unroll
            for (int cb = 0; cb < 4; ++cb)
#pragma unroll
                for (int r = 0; r < 4; ++r) {
                    float e = __expf(sv[cb][r] - mnew);
                    pv[cb][r] = e;
                    rs += e;
                }
            rs += __shfl_xor(rs, 16);
            rs += __shfl_xor(rs, 32);
            l_[g] = l_[g] * alpha + rs;
            m_[g] = mnew;
#pragma unroll
            for (int cb = 0; cb < 4; ++cb) {
#pragma unroll
                for (int r = 0; r < 4; ++r) oacc[g][cb][r] *= alpha;
                uint2 pk = { pack2(pv[cb][0], pv[cb][1]), pack2(pv[cb][2], pv[cb][3]) };
                *(uint2*)&Ps[(g * 16 + n) * 144 + cb * 32 + qd * 8] = pk;
            }
        }

#pragma unroll
        for (int ks = 0; ks < 2; ++ks) {
            v8s pf[2];
#pragma unroll
            for (int g = 0; g < 2; ++g)
                pf[g] = *(const v8s*)&Ps[(g * 16 + n) * 144 + ks * 64 + qd * 16];
#pragma unroll
            for (int cb = 0; cb < 4; ++cb) {
                v8s vf = *(const v8s*)&Vts[(cb * 16 + n) * 144 + ks * 64 + qd * 16];
#pragma unroll
                for (int g = 0; g < 2; ++g)
                    oacc[g][cb] = __builtin_amdgcn_mfma_f32_16x16x32_bf16(vf, pf[g], oacc[g][cb], 0, 0, 0);
            }
        }
    }

    // ---- epilogue
    if (SPLITS == 1) {
#pragma unroll
        for (int g = 0; g < 2; ++g) {
            const float inv = 1.0f / l_[g];
#pragma unroll
            for (int cb = 0; cb < 4; ++cb)
#pragma unroll
                for (int r = 0; r < 4; ++r) oacc[g][cb][r] *= inv;
        }
    } else {
        if (qd == 0) {   // lanes 0..15 hold (m,l) for rows g*16+n (dup across qd)
#pragma unroll
            for (int g = 0; g < 2; ++g) {
                const size_t row = (size_t)bh * SEQ + rb * 128 + w * 32 + g * 16 + n;
                ml[((size_t)kq * NROWS + row) * 2 + 0] = m_[g];
                ml[((size_t)kq * NROWS + row) * 2 + 1] = l_[g];
            }
        }
    }
    __syncthreads();
#pragma unroll
    for (int g = 0; g < 2; ++g)
#pragma unroll
        for (int cb = 0; cb < 4; ++cb)
            *(v4f*)&smem[(w * 32 + g * 16 + n) * 272 + cb * 64 + qd * 16] = oacc[g][cb];
    __syncthreads();
    const int r_l = tid >> 1, hf = tid & 1;
    float* dst = (SPLITS == 1)
        ? &out[((size_t)bh * SEQ + rb * 128 + r_l) * DH + hf * 32]
        : &Opart[((size_t)kq * NROWS + (size_t)bh * SEQ + rb * 128 + r_l) * DH + hf * 32];
#pragma unroll
    for (int i = 0; i < 8; ++i) {
        float4 t4 = *(const float4*)&smem[r_l * 272 + hf * 128 + i * 16];
        *(float4*)&dst[i * 4] = t4;
    }
}

// ---------------------------------------------------------------------------
// Combine split-K partials: out[row] = sum_s w_s*O_s[row] / sum_s w_s*l_s,
// w_s = exp(m_s - max m). 16 rows/block, 16 threads/row (one float4 of d each).
// ---------------------------------------------------------------------------
__global__ __launch_bounds__(256) void combine_kernel(
    const float* __restrict__ Opart, const float* __restrict__ ml,
    float* __restrict__ out, int splits)
{
    const int tid = threadIdx.x;
    const size_t row = (size_t)blockIdx.x * 16 + (tid >> 4);
    const int d4 = (tid & 15) * 4;
    float M = -1e30f;
    for (int s = 0; s < splits; ++s)
        M = fmaxf(M, ml[((size_t)s * NROWS + row) * 2]);
    float denom = 0.f;
    float4 o = make_float4(0.f, 0.f, 0.f, 0.f);
    for (int s = 0; s < splits; ++s) {
        const float ws = __expf(ml[((size_t)s * NROWS + row) * 2] - M);
        denom += ws * ml[((size_t)s * NROWS + row) * 2 + 1];
        float4 p = *(const float4*)&Opart[((size_t)s * NROWS + row) * DH + d4];
        o.x += ws * p.x; o.y += ws * p.y; o.z += ws * p.z; o.w += ws * p.w;
    }
    const float inv = 1.0f / denom;
    o.x *= inv; o.y *= inv; o.z *= inv; o.w *= inv;
    *(float4*)&out[row * DH + d4] = o;
}

extern "C" void kernel_launch(void* const* d_in, const int* in_sizes, int n_in,
                              void* d_out, int out_size, void* d_ws, size_t ws_size,
                              hipStream_t stream) {
    const float* q    = (const float*)d_in[0];
    const float* k    = (const float*)d_in[1];
    const float* v    = (const float*)d_in[2];
    const float* mask = (const float*)d_in[3];
    const float* Wq   = (const float*)d_in[4];
    const float* bq   = (const float*)d_in[5];
    const float* Wk   = (const float*)d_in[6];
    const float* bk   = (const float*)d_in[7];
    const float* Wv   = (const float*)d_in[8];
    const float* bv   = (const float*)d_in[9];

    unsigned short* Qbf = (unsigned short*)d_ws;                   // 4 MB
    unsigned short* Kbf = Qbf + (size_t)MROWS * EMB;               // 4 MB
    unsigned short* Vbf = Kbf + (size_t)MROWS * EMB;               // 4 MB
    unsigned short* VtG = Vbf + (size_t)MROWS * EMB;               // 4 MB
    float* Opart = (float*)(VtG + (size_t)MROWS * EMB);            // SPLITS x 8 MB
    float* ml    = Opart + (size_t)4 * NROWS * DH;                 // 4 x 256 KB

    const size_t need_split = (size_t)16 * 1024 * 1024              // bf16 bufs
                            + (size_t)4 * NROWS * DH * 4            // Opart x4
                            + (size_t)4 * NROWS * 2 * 4;            // ml x4
    const bool do_split = ws_size >= need_split;

    dim3 pgrid(EMB / 128, MROWS / 128, 3);   // 4 x 32 x 3 = 384 blocks
    proj_kernel<<<pgrid, 256, 0, stream>>>(q, k, v, Wq, bq, Wk, bk, Wv, bv,
                                           Qbf, Kbf, Vbf);

    dim3 tgrid(16, SEQ / 128);
    vtrans_kernel<<<tgrid, 256, 0, stream>>>(Vbf, VtG);

    if (do_split) {
        dim3 agrid(16, SEQ / 128, 4);        // 1024 blocks -> 4 blocks/CU
        attn_kernel<4><<<agrid, 256, 0, stream>>>(Qbf, Kbf, VtG, mask,
                                                  Opart, ml, (float*)d_out);
        combine_kernel<<<NROWS / 16, 256, 0, stream>>>(Opart, ml, (float*)d_out, 4);
    } else {
        dim3 agrid(16, SEQ / 128, 1);
        attn_kernel<1><<<agrid, 256, 0, stream>>>(Qbf, Kbf, VtG, mask,
                                                  Opart, ml, (float*)d_out);
    }
}